// Round 1
// baseline (164.263 us; speedup 1.0000x reference)
//
#include <hip/hip_runtime.h>
#include <math.h>

// ws layout (floats):
//   [0 .. 12*B-1]   : per-batch {M[9] = R'-I (row-major), t'[3]}
//   [12*B + 0]      : loss_transl
//   [12*B + 1]      : loss_rot
//   [12*B + 2]      : sum_err accumulator (zeroed by pose kernel)

__device__ inline void quat_to_rot(float q0, float q1, float q2, float q3,
                                   float R[3][3]) {
    float inv_n = rsqrtf(q0 * q0 + q1 * q1 + q2 * q2 + q3 * q3);
    float w = q0 * inv_n, x = q1 * inv_n, y = q2 * inv_n, z = q3 * inv_n;
    R[0][0] = 1.f - 2.f * y * y - 2.f * z * z;
    R[0][1] = 2.f * x * y - 2.f * z * w;
    R[0][2] = 2.f * x * z + 2.f * y * w;
    R[1][0] = 2.f * x * y + 2.f * z * w;
    R[1][1] = 1.f - 2.f * x * x - 2.f * z * z;
    R[1][2] = 2.f * y * z - 2.f * x * w;
    R[2][0] = 2.f * x * z - 2.f * y * w;
    R[2][1] = 2.f * y * z + 2.f * x * w;
    R[2][2] = 1.f - 2.f * x * x - 2.f * y * y;
}

// One block of 64 threads; thread b < B handles batch b.
__global__ __launch_bounds__(64) void pose_kernel(
    const float* __restrict__ target_transl, const float* __restrict__ target_rot,
    const float* __restrict__ transl_err, const float* __restrict__ rot_err,
    float* __restrict__ ws, int B) {
    int b = threadIdx.x;
    float s = 0.f, dang = 0.f;
    if (b < B) {
        // smooth L1 (beta=1), summed over the 3 components
        for (int i = 0; i < 3; i++) {
            float d = fabsf(transl_err[b * 3 + i] - target_transl[b * 3 + i]);
            s += (d < 1.f) ? 0.5f * d * d : d - 0.5f;
        }
        // quaternion angular distance (degrees), raw (unnormalized) quats
        float q0 = rot_err[b * 4 + 0], q1 = rot_err[b * 4 + 1];
        float q2 = rot_err[b * 4 + 2], q3 = rot_err[b * 4 + 3];
        float r0 = target_rot[b * 4 + 0], r1 = -target_rot[b * 4 + 1];
        float r2 = -target_rot[b * 4 + 2], r3 = -target_rot[b * 4 + 3];
        float w = q0 * r0 - q1 * r1 - q2 * r2 - q3 * r3;
        float x = q0 * r1 + q1 * r0 + q2 * r3 - q3 * r2;
        float y = q0 * r2 - q1 * r3 + q2 * r0 + q3 * r1;
        float z = q0 * r3 + q1 * r2 - q2 * r1 + q3 * r0;
        dang = 2.0f * atan2f(sqrtf(x * x + y * y + z * z), fabsf(w)) *
               (180.0f / 3.14159265358979323846f);

        // RT_inv = inv(RT_pred) @ RT_target = [Rp^T Rt | Rp^T (tt - tp)]
        float Rt[3][3], Rp[3][3];
        quat_to_rot(target_rot[b * 4 + 0], target_rot[b * 4 + 1],
                    target_rot[b * 4 + 2], target_rot[b * 4 + 3], Rt);
        quat_to_rot(rot_err[b * 4 + 0], rot_err[b * 4 + 1],
                    rot_err[b * 4 + 2], rot_err[b * 4 + 3], Rp);
        float dt[3];
        for (int k = 0; k < 3; k++)
            dt[k] = target_transl[b * 3 + k] - transl_err[b * 3 + k];
        float* mp = ws + b * 12;
        for (int i = 0; i < 3; i++) {
            for (int j = 0; j < 3; j++) {
                float v = Rp[0][i] * Rt[0][j] + Rp[1][i] * Rt[1][j] +
                          Rp[2][i] * Rt[2][j];
                mp[3 * i + j] = v - (i == j ? 1.f : 0.f);  // M = R' - I
            }
            mp[9 + i] = Rp[0][i] * dt[0] + Rp[1][i] * dt[1] + Rp[2][i] * dt[2];
        }
    }
    // wave-64 reduction (inactive lanes contribute 0)
    for (int off = 32; off > 0; off >>= 1) {
        s += __shfl_down(s, off);
        dang += __shfl_down(dang, off);
    }
    if (threadIdx.x == 0) {
        ws[12 * B + 0] = s / (float)B;
        ws[12 * B + 1] = dang / (float)B;
        ws[12 * B + 2] = 0.f;  // zero the accumulator (ws is poisoned 0xAA)
    }
}

__device__ inline float err_pt(float x, float y, float z, float m00, float m01,
                               float m02, float m10, float m11, float m12,
                               float m20, float m21, float m22, float t0,
                               float t1, float t2) {
    float dx = m00 * x + m01 * y + m02 * z + t0;
    float dy = m10 * x + m11 * y + m12 * z + t1;
    float dz = m20 * x + m21 * y + m22 * z + t2;
    return sqrtf(dx * dx + dy * dy + dz * dz);
}

// grid: (gx, B); each block reduces its partial into acc via one atomicAdd.
__global__ __launch_bounds__(256) void pc_kernel(const float* __restrict__ pc,
                                                 const float* __restrict__ ws,
                                                 float* __restrict__ acc,
                                                 int N, int B) {
    int b = blockIdx.y;
    const float* mp = ws + b * 12;  // block-uniform -> scalar loads
    float m00 = mp[0], m01 = mp[1], m02 = mp[2];
    float m10 = mp[3], m11 = mp[4], m12 = mp[5];
    float m20 = mp[6], m21 = mp[7], m22 = mp[8];
    float t0 = mp[9], t1 = mp[10], t2 = mp[11];

    const float* xrow = pc + (size_t)b * 4 * N;
    const float* yrow = xrow + N;
    const float* zrow = yrow + N;

    float local = 0.f;
    if ((N & 3) == 0) {
        int nG = N >> 2;
        const float4* x4p = (const float4*)xrow;
        const float4* y4p = (const float4*)yrow;
        const float4* z4p = (const float4*)zrow;
        for (int g = blockIdx.x * blockDim.x + threadIdx.x; g < nG;
             g += gridDim.x * blockDim.x) {
            float4 x4 = x4p[g], y4 = y4p[g], z4 = z4p[g];
            local += err_pt(x4.x, y4.x, z4.x, m00, m01, m02, m10, m11, m12,
                            m20, m21, m22, t0, t1, t2);
            local += err_pt(x4.y, y4.y, z4.y, m00, m01, m02, m10, m11, m12,
                            m20, m21, m22, t0, t1, t2);
            local += err_pt(x4.z, y4.z, z4.z, m00, m01, m02, m10, m11, m12,
                            m20, m21, m22, t0, t1, t2);
            local += err_pt(x4.w, y4.w, z4.w, m00, m01, m02, m10, m11, m12,
                            m20, m21, m22, t0, t1, t2);
        }
    } else {  // generic fallback (unused for N % 4 == 0)
        for (int n = blockIdx.x * blockDim.x + threadIdx.x; n < N;
             n += gridDim.x * blockDim.x) {
            local += err_pt(xrow[n], yrow[n], zrow[n], m00, m01, m02, m10, m11,
                            m12, m20, m21, m22, t0, t1, t2);
        }
    }

    // block reduction: wave shuffle -> LDS -> one atomic
    __shared__ float smem[4];
    for (int off = 32; off > 0; off >>= 1) local += __shfl_down(local, off);
    int lane = threadIdx.x & 63, wid = threadIdx.x >> 6;
    if (lane == 0) smem[wid] = local;
    __syncthreads();
    if (threadIdx.x == 0) {
        float v = smem[0] + smem[1] + smem[2] + smem[3];
        atomicAdd(acc, v);
    }
}

__global__ __launch_bounds__(64) void final_kernel(const float* __restrict__ ws,
                                                   float* __restrict__ out,
                                                   int B, int N) {
    if (threadIdx.x == 0) {
        float lt = ws[12 * B + 0];
        float lr = ws[12 * B + 1];
        float sum_err = ws[12 * B + 2];
        float pcl = sum_err / (float)N;      // point_clouds_loss
        float pclB = pcl / (float)B;         // point_clouds_loss / B
        float pose = lt + lr;                // rescale_trans = rescale_rot = 1
        float total = 0.5f * pose + 0.5f * pclB;  // weight_pc = 0.5
        out[0] = total;
        out[1] = lt;
        out[2] = lr;
        out[3] = pclB;
    }
}

extern "C" void kernel_launch(void* const* d_in, const int* in_sizes, int n_in,
                              void* d_out, int out_size, void* d_ws,
                              size_t ws_size, hipStream_t stream) {
    const float* pc = (const float*)d_in[0];
    const float* target_transl = (const float*)d_in[1];
    const float* target_rot = (const float*)d_in[2];
    const float* transl_err = (const float*)d_in[3];
    const float* rot_err = (const float*)d_in[4];
    float* out = (float*)d_out;
    float* ws = (float*)d_ws;

    int B = in_sizes[1] / 3;               // target_transl is [B,3]
    int N = in_sizes[0] / (4 * B);         // point_clouds is [B,4,N]

    pose_kernel<<<1, 64, 0, stream>>>(target_transl, target_rot, transl_err,
                                      rot_err, ws, B);

    float* acc = ws + 12 * B + 2;
    dim3 grid2(64, B);
    pc_kernel<<<grid2, 256, 0, stream>>>(pc, ws, acc, N, B);

    final_kernel<<<1, 64, 0, stream>>>(ws, out, B, N);
}

// Round 2
// 152.061 us; speedup vs baseline: 1.0802x; 1.0802x over previous
//
#include <hip/hip_runtime.h>
#include <math.h>

// ws layout (floats): [0 .. GX*B-1] per-block partial sums of err.
// GX = 64 blocks along x, B batches along y -> 2048 partials, every slot
// written every call (no init, no atomics, deterministic).

#define GX 64

__device__ inline void quat_to_rot(float q0, float q1, float q2, float q3,
                                   float R[3][3]) {
    float inv_n = rsqrtf(q0 * q0 + q1 * q1 + q2 * q2 + q3 * q3);
    float w = q0 * inv_n, x = q1 * inv_n, y = q2 * inv_n, z = q3 * inv_n;
    R[0][0] = 1.f - 2.f * y * y - 2.f * z * z;
    R[0][1] = 2.f * x * y - 2.f * z * w;
    R[0][2] = 2.f * x * z + 2.f * y * w;
    R[1][0] = 2.f * x * y + 2.f * z * w;
    R[1][1] = 1.f - 2.f * x * x - 2.f * z * z;
    R[1][2] = 2.f * y * z - 2.f * x * w;
    R[2][0] = 2.f * x * z - 2.f * y * w;
    R[2][1] = 2.f * y * z + 2.f * x * w;
    R[2][2] = 1.f - 2.f * x * x - 2.f * y * y;
}

__device__ inline float err_pt(float x, float y, float z, float m00, float m01,
                               float m02, float m10, float m11, float m12,
                               float m20, float m21, float m22, float t0,
                               float t1, float t2) {
    float dx = m00 * x + m01 * y + m02 * z + t0;
    float dy = m10 * x + m11 * y + m12 * z + t1;
    float dz = m20 * x + m21 * y + m22 * z + t2;
    return sqrtf(dx * dx + dy * dy + dz * dz);
}

// grid: (GX, B). Each block computes its batch's M = R'-I and t' redundantly
// (all inputs wave-uniform -> scalarized), streams its slice of x/y/z rows,
// and writes ONE partial to partials[b*GX + gx]. No atomics, no ws reads.
__global__ __launch_bounds__(256) void pc_kernel(
    const float* __restrict__ pc, const float* __restrict__ target_transl,
    const float* __restrict__ target_rot, const float* __restrict__ transl_err,
    const float* __restrict__ rot_err, float* __restrict__ partials, int N) {
    int b = blockIdx.y;  // wave-uniform

    // RT_inv = inv(RT_pred) @ RT_target = [Rp^T Rt | Rp^T (tt - tp)]
    float Rt[3][3], Rp[3][3];
    quat_to_rot(target_rot[b * 4 + 0], target_rot[b * 4 + 1],
                target_rot[b * 4 + 2], target_rot[b * 4 + 3], Rt);
    quat_to_rot(rot_err[b * 4 + 0], rot_err[b * 4 + 1], rot_err[b * 4 + 2],
                rot_err[b * 4 + 3], Rp);
    float dt0 = target_transl[b * 3 + 0] - transl_err[b * 3 + 0];
    float dt1 = target_transl[b * 3 + 1] - transl_err[b * 3 + 1];
    float dt2 = target_transl[b * 3 + 2] - transl_err[b * 3 + 2];
    // M = Rp^T Rt - I (row i, col j), t' = Rp^T dt
    float m00 = Rp[0][0] * Rt[0][0] + Rp[1][0] * Rt[1][0] + Rp[2][0] * Rt[2][0] - 1.f;
    float m01 = Rp[0][0] * Rt[0][1] + Rp[1][0] * Rt[1][1] + Rp[2][0] * Rt[2][1];
    float m02 = Rp[0][0] * Rt[0][2] + Rp[1][0] * Rt[1][2] + Rp[2][0] * Rt[2][2];
    float m10 = Rp[0][1] * Rt[0][0] + Rp[1][1] * Rt[1][0] + Rp[2][1] * Rt[2][0];
    float m11 = Rp[0][1] * Rt[0][1] + Rp[1][1] * Rt[1][1] + Rp[2][1] * Rt[2][1] - 1.f;
    float m12 = Rp[0][1] * Rt[0][2] + Rp[1][1] * Rt[1][2] + Rp[2][1] * Rt[2][2];
    float m20 = Rp[0][2] * Rt[0][0] + Rp[1][2] * Rt[1][0] + Rp[2][2] * Rt[2][0];
    float m21 = Rp[0][2] * Rt[0][1] + Rp[1][2] * Rt[1][1] + Rp[2][2] * Rt[2][1];
    float m22 = Rp[0][2] * Rt[0][2] + Rp[1][2] * Rt[1][2] + Rp[2][2] * Rt[2][2] - 1.f;
    float t0 = Rp[0][0] * dt0 + Rp[1][0] * dt1 + Rp[2][0] * dt2;
    float t1 = Rp[0][1] * dt0 + Rp[1][1] * dt1 + Rp[2][1] * dt2;
    float t2 = Rp[0][2] * dt0 + Rp[1][2] * dt1 + Rp[2][2] * dt2;

    const float* xrow = pc + (size_t)b * 4 * N;
    const float* yrow = xrow + N;
    const float* zrow = yrow + N;

    float local = 0.f;
    if ((N & 3) == 0) {
        int nG = N >> 2;
        const float4* x4p = (const float4*)xrow;
        const float4* y4p = (const float4*)yrow;
        const float4* z4p = (const float4*)zrow;
        for (int g = blockIdx.x * blockDim.x + threadIdx.x; g < nG;
             g += GX * blockDim.x) {
            float4 x4 = x4p[g], y4 = y4p[g], z4 = z4p[g];
            local += err_pt(x4.x, y4.x, z4.x, m00, m01, m02, m10, m11, m12,
                            m20, m21, m22, t0, t1, t2);
            local += err_pt(x4.y, y4.y, z4.y, m00, m01, m02, m10, m11, m12,
                            m20, m21, m22, t0, t1, t2);
            local += err_pt(x4.z, y4.z, z4.z, m00, m01, m02, m10, m11, m12,
                            m20, m21, m22, t0, t1, t2);
            local += err_pt(x4.w, y4.w, z4.w, m00, m01, m02, m10, m11, m12,
                            m20, m21, m22, t0, t1, t2);
        }
    } else {
        for (int n = blockIdx.x * blockDim.x + threadIdx.x; n < N;
             n += GX * blockDim.x) {
            local += err_pt(xrow[n], yrow[n], zrow[n], m00, m01, m02, m10, m11,
                            m12, m20, m21, m22, t0, t1, t2);
        }
    }

    // block reduction: wave shuffle -> LDS -> single store (no atomics)
    __shared__ float smem[4];
    for (int off = 32; off > 0; off >>= 1) local += __shfl_down(local, off);
    int lane = threadIdx.x & 63, wid = threadIdx.x >> 6;
    if (lane == 0) smem[wid] = local;
    __syncthreads();
    if (threadIdx.x == 0)
        partials[blockIdx.y * GX + blockIdx.x] =
            smem[0] + smem[1] + smem[2] + smem[3];
}

// One block, 256 threads: reduce GX*B partials + pose loss + write outputs.
__global__ __launch_bounds__(256) void finalize_kernel(
    const float* __restrict__ partials, int nPart,
    const float* __restrict__ target_transl,
    const float* __restrict__ target_rot,
    const float* __restrict__ transl_err, const float* __restrict__ rot_err,
    float* __restrict__ out, int B, int N) {
    // ---- partial-sum reduction (all 256 threads) ----
    float s = 0.f;
    for (int i = threadIdx.x; i < nPart; i += 256) s += partials[i];
    for (int off = 32; off > 0; off >>= 1) s += __shfl_down(s, off);
    __shared__ float smem[4];
    int lane = threadIdx.x & 63, wid = threadIdx.x >> 6;
    if (lane == 0) smem[wid] = s;
    __syncthreads();

    // ---- pose loss (threads 0..B-1, B <= 64 assumed) ----
    float st = 0.f, dang = 0.f;
    int b = threadIdx.x;
    if (b < B) {
        for (int i = 0; i < 3; i++) {
            float d = fabsf(transl_err[b * 3 + i] - target_transl[b * 3 + i]);
            st += (d < 1.f) ? 0.5f * d * d : d - 0.5f;
        }
        float q0 = rot_err[b * 4 + 0], q1 = rot_err[b * 4 + 1];
        float q2 = rot_err[b * 4 + 2], q3 = rot_err[b * 4 + 3];
        float r0 = target_rot[b * 4 + 0], r1 = -target_rot[b * 4 + 1];
        float r2 = -target_rot[b * 4 + 2], r3 = -target_rot[b * 4 + 3];
        float w = q0 * r0 - q1 * r1 - q2 * r2 - q3 * r3;
        float x = q0 * r1 + q1 * r0 + q2 * r3 - q3 * r2;
        float y = q0 * r2 - q1 * r3 + q2 * r0 + q3 * r1;
        float z = q0 * r3 + q1 * r2 - q2 * r1 + q3 * r0;
        dang = 2.0f * atan2f(sqrtf(x * x + y * y + z * z), fabsf(w)) *
               (180.0f / 3.14159265358979323846f);
    }
    if (threadIdx.x < 64) {  // wave-uniform branch; reduce within wave 0
        for (int off = 32; off > 0; off >>= 1) {
            st += __shfl_down(st, off);
            dang += __shfl_down(dang, off);
        }
    }

    if (threadIdx.x == 0) {
        float sum_err = smem[0] + smem[1] + smem[2] + smem[3];
        float lt = st / (float)B;
        float lr = dang / (float)B;
        float pclB = sum_err / (float)N / (float)B;  // point_clouds_loss / B
        out[0] = 0.5f * (lt + lr) + 0.5f * pclB;     // weight_pc = 0.5
        out[1] = lt;
        out[2] = lr;
        out[3] = pclB;
    }
}

extern "C" void kernel_launch(void* const* d_in, const int* in_sizes, int n_in,
                              void* d_out, int out_size, void* d_ws,
                              size_t ws_size, hipStream_t stream) {
    const float* pc = (const float*)d_in[0];
    const float* target_transl = (const float*)d_in[1];
    const float* target_rot = (const float*)d_in[2];
    const float* transl_err = (const float*)d_in[3];
    const float* rot_err = (const float*)d_in[4];
    float* out = (float*)d_out;
    float* partials = (float*)d_ws;

    int B = in_sizes[1] / 3;        // target_transl is [B,3]
    int N = in_sizes[0] / (4 * B);  // point_clouds is [B,4,N]

    dim3 grid(GX, B);
    pc_kernel<<<grid, 256, 0, stream>>>(pc, target_transl, target_rot,
                                        transl_err, rot_err, partials, N);
    finalize_kernel<<<1, 256, 0, stream>>>(partials, GX * B, target_transl,
                                           target_rot, transl_err, rot_err,
                                           out, B, N);
}